// Round 14
// baseline (803.771 us; speedup 1.0000x reference)
//
#include <hip/hip_runtime.h>

#define NPTS 288
#define DIMS 2048
#define KC   6
#define N_IT 25

// ---------------- k_gram: partial G = A^T A, UPPER tile-pairs only ----------------
// (round-12 config, verbatim: proven 260 us at its LDS-feed ceiling, VGPR 92)
#define GT   96
#define KB   32
#define KSPL 2
#define KPS  (DIMS / KSPL)   // 1024
#define NCH  (KPS / KB)      // 32 chunks
#define NTP  6               // upper tile-pairs: (0,0)(0,1)(0,2)(1,1)(1,2)(2,2)

#define GLD16(gp, lp) __builtin_amdgcn_global_load_lds(                      \
    (const __attribute__((address_space(1))) void*)(gp),                     \
    (__attribute__((address_space(3))) void*)(lp), 16, 0, 0)

__global__ __launch_bounds__(256, 2) void k_gram(const float* __restrict__ x,
                                                 float* __restrict__ Gp, int nb) {
  const int bid = blockIdx.x;
  const int b  = bid / (NTP * KSPL);
  const int r0 = bid - b * (NTP * KSPL);
  const int ks = r0 / NTP, pr = r0 - ks * NTP;
  const int ti = (pr < 3) ? 0 : ((pr < 5) ? 1 : 2);
  const int tj = (pr < 3) ? pr : ((pr < 5) ? (pr - 2) : 2);
  const int t = threadIdx.x;
  const int tr = t >> 4, tc = t & 15;
  const int w = t >> 6, l = t & 63;
  const float* __restrict__ xb = x + (size_t)b * (DIMS * NPTS);
  float* __restrict__ Gb = Gp + ((size_t)ks * nb + b) * (NPTS * NPTS);

  __shared__ __attribute__((aligned(16))) float bufA[2][KB][GT];   // 24.6 KB
  __shared__ __attribute__((aligned(16))) float bufB[2][KB][GT];   // 24.6 KB

  int off[3];
#pragma unroll
  for (int iq = 0; iq < 3; ++iq) {
    const int e = (w * 3 + iq) * 256 + 4 * l;
    off[iq] = (e / GT) * NPTS + (e - (e / GT) * GT);
  }
  const float* __restrict__ baseA = xb + (size_t)(ks * KPS) * NPTS + ti * GT;
  const float* __restrict__ baseB = xb + (size_t)(ks * KPS) * NPTS + tj * GT;

  float acc[6][6];
#pragma unroll
  for (int ii = 0; ii < 6; ++ii)
#pragma unroll
    for (int jj = 0; jj < 6; ++jj) acc[ii][jj] = 0.f;

  auto stage = [&](int n, int c) {
#pragma unroll
    for (int iq = 0; iq < 3; ++iq) {
      const int o   = off[iq] + c * (KB * NPTS);
      const int lw  = (w * 3 + iq) * 256;
      GLD16(baseA + o, &bufA[n][0][0] + lw);
      GLD16(baseB + o, &bufB[n][0][0] + lw);
    }
  };

  stage(0, 0);
  __syncthreads();
  int n = 0;
  for (int c = 0; c < NCH; ++c) {
    if (c + 1 < NCH) stage(n ^ 1, c + 1);
#pragma unroll
    for (int kk = 0; kk < KB; ++kk) {
      float af[6], bf[6];
      const float2 a01 = *(const float2*)&bufA[n][kk][6 * tr];
      const float2 a23 = *(const float2*)&bufA[n][kk][6 * tr + 2];
      const float2 a45 = *(const float2*)&bufA[n][kk][6 * tr + 4];
      const float2 b01 = *(const float2*)&bufB[n][kk][6 * tc];
      const float2 b23 = *(const float2*)&bufB[n][kk][6 * tc + 2];
      const float2 b45 = *(const float2*)&bufB[n][kk][6 * tc + 4];
      af[0] = a01.x; af[1] = a01.y; af[2] = a23.x; af[3] = a23.y; af[4] = a45.x; af[5] = a45.y;
      bf[0] = b01.x; bf[1] = b01.y; bf[2] = b23.x; bf[3] = b23.y; bf[4] = b45.x; bf[5] = b45.y;
#pragma unroll
      for (int ii = 0; ii < 6; ++ii)
#pragma unroll
        for (int jj = 0; jj < 6; ++jj) acc[ii][jj] += af[ii] * bf[jj];
    }
    __syncthreads();
    n ^= 1;
  }

#pragma unroll
  for (int ii = 0; ii < 6; ++ii) {
    const int ri = ti * GT + 6 * tr + ii;
#pragma unroll
    for (int jj = 0; jj < 6; ++jj)
      Gb[(size_t)ri * NPTS + tj * GT + 6 * tc + jj] = acc[ii][jj];
  }
}

// ---------------- k_gsum: G = Gp0 + Gp1, all-coalesced mirror via LDS bounce ----------------
// One block per (batch, upper tile-pair). Reads partial tiles coalesced, writes
// (ti,tj) directly + (tj,ti) transposed through a 96x97-padded LDS tile
// (stride 97 == 1 mod 32 -> conflict-free transposed reads). Diagonal tiles are
// bitwise symmetric (commuted products, same kk order) -> no mirror needed.
__global__ __launch_bounds__(256) void k_gsum(const float* __restrict__ Gp,
                                              float* __restrict__ G, int nb) {
  const int bid = blockIdx.x;
  const int b = bid / NTP, pr = bid - b * NTP;
  const int ti = (pr < 3) ? 0 : ((pr < 5) ? 1 : 2);
  const int tj = (pr < 3) ? pr : ((pr < 5) ? (pr - 2) : 2);
  const int t = threadIdx.x;
  const size_t N2 = (size_t)NPTS * NPTS;
  const size_t p1 = (size_t)nb * N2;
  const float* __restrict__ s0 = Gp + (size_t)b * N2;
  const float* __restrict__ s1 = Gp + p1 + (size_t)b * N2;
  float* __restrict__ Gb = G + (size_t)b * N2;

  __shared__ float tl[GT * 97];   // 37.2 KB

#pragma unroll
  for (int q = 0; q < 36; ++q) {
    const int e = q * 256 + t;           // 0..9215
    const int lr = e / GT, lc = e - lr * GT;
    const size_t idx = (size_t)(ti * GT + lr) * NPTS + tj * GT + lc;
    const float v = s0[idx] + s1[idx];   // fixed order: deterministic
    Gb[idx] = v;                         // coalesced
    tl[lr * 97 + lc] = v;                // stride-1 LDS write
  }
  if (ti == tj) return;                  // block-uniform: symmetric tile, no mirror
  __syncthreads();
#pragma unroll
  for (int q = 0; q < 36; ++q) {
    const int e = q * 256 + t;
    const int lr = e / GT, lc = e - lr * GT;     // output-local row/col at (tj,ti)
    Gb[(size_t)(tj * GT + lr) * NPTS + ti * GT + lc] = tl[lc * 97 + lr];  // coalesced out
  }
}

// ---------------- k_lloyd: all 25 Lloyd iterations on G (sparse-u) ----------------
// u-step exploits 1-sparse w columns: gather-sum by previous assignment (1 add vs
// 6 FMA per G element), normalize by rn[k]=1/n_k. Frozen (empty) clusters keep
// their previous u/w2/csq exactly (freeze chain preserved).
__global__ __launch_bounds__(1024) void k_lloyd(const float* __restrict__ G,
                                                float* __restrict__ wg, int nb) {
  const int b = blockIdx.x;
  const int t = threadIdx.x, wv = t >> 6, lane = t & 63;
  const float* __restrict__ Gb = G + (size_t)b * (NPTS * NPTS);

  __shared__ float w2[NPTS][8];          //  9.2 KB  weights [point][k], pad 8
  __shared__ float pool[KC][NPTS][5];    // 34.6 KB  u partials (3 used, pad 5)
  __shared__ float u[NPTS * KC > 0 ? KC : KC][NPTS];  //  6.9 KB
  __shared__ int assign_s[NPTS];
  __shared__ float csq[KC];
  __shared__ int cnt_i[KC];
  __shared__ float rn_s[KC];
  __shared__ int live_s[KC];

  // init: w_k = e_k  (centers0 = first KC points)
  for (int e = t; e < NPTS * 8; e += 1024) {
    const int i = e >> 3, k = e & 7;
    w2[i][k] = (k < KC && i == k) ? 1.f : 0.f;
  }
  __syncthreads();

  for (int it = 0; it < N_IT; ++it) {
    // capture prev counts -> rn/live, then reset counts (same thread, no race)
    if (t < KC) {
      const int cn = cnt_i[t];           // garbage at it==0 (unused then)
      live_s[t] = (cn > 0) ? 1 : 0;
      rn_s[t]   = (cn > 0) ? (1.0f / (float)cn) : 0.f;
      cnt_i[t] = 0;
    }
    __syncthreads();

    if (it == 0) {
      // u[k][i] = G[i][k]  (w = e_k exactly)
      if (t < NPTS) {
#pragma unroll
        for (int k = 0; k < KC; ++k) u[k][t] = Gb[(size_t)t * NPTS + k];
      }
    } else {
      // sparse gather: waves 0-14, jg = row third, lanes <-> cols i
      const int jg = t / 320;            // wave-uniform
      const int i  = t - jg * 320;
      if (t < 960 && i < NPTS) {
        float s0 = 0, s1 = 0, s2 = 0, s3 = 0, s4 = 0, s5 = 0;
        const float* __restrict__ gp = Gb + (size_t)(jg * 96) * NPTS + i;
        const int jb = jg * 96;
        for (int jj = 0; jj < 96; ++jj) {
          const float g = gp[(size_t)jj * NPTS];          // coalesced (rows of G)
          const int a = __builtin_amdgcn_readfirstlane(assign_s[jb + jj]);
          if      (a == 0) s0 += g;
          else if (a == 1) s1 += g;
          else if (a == 2) s2 += g;
          else if (a == 3) s3 += g;
          else if (a == 4) s4 += g;
          else             s5 += g;
        }
        pool[0][i][jg] = s0; pool[1][i][jg] = s1; pool[2][i][jg] = s2;
        pool[3][i][jg] = s3; pool[4][i][jg] = s4; pool[5][i][jg] = s5;
      }
    }
    __syncthreads();
    if (it > 0) {
      // u reduce + normalize (fixed order); frozen k keeps old u
      for (int e = t; e < KC * NPTS; e += 1024) {
        const int k = e / NPTS, i = e - k * NPTS;
        if (live_s[k])
          u[k][i] = (pool[k][i][0] + pool[k][i][1] + pool[k][i][2]) * rn_s[k];
      }
      __syncthreads();
    }

    // ---- csq_k = w_k^T u_k : wave k, lane-strided + shuffle tree (fixed order) ----
    if (wv < KC) {
      float s = 0.f;
      for (int i = lane; i < NPTS; i += 64) s += w2[i][wv] * u[wv][i];
#pragma unroll
      for (int off = 32; off; off >>= 1) s += __shfl_xor(s, off, 64);
      if (lane == 0) csq[wv] = s;
    }
    __syncthreads();
    // ---- scores + argmin + counts ----
    int myA = -1;
    if (t < NPTS) {
      float best = 0.f;
      int bi = 0;
#pragma unroll
      for (int k = 0; k < KC; ++k) {
        const float sc = 0.5f * csq[k] - u[k][t];   // argmin_k(dist) equivalent
        if (k == 0 || sc < best) { best = sc; bi = k; }   // strict < : first-min
      }
      assign_s[t] = bi;
      myA = bi;
    }
    if (t < 320) {   // waves 0-4, uniform predicate; int atomics: deterministic
#pragma unroll
      for (int k = 0; k < KC; ++k) {
        unsigned long long m = __ballot(myA == k);
        if (lane == 0) atomicAdd(&cnt_i[k], (int)__popcll(m));
      }
    }
    __syncthreads();
    // ---- w update: live clusters get a_k/n_k, empty keep old weights ----
    if (t < NPTS) {
      const int a = assign_s[t];
#pragma unroll
      for (int k = 0; k < KC; ++k) {
        const int cn = cnt_i[k];
        if (cn > 0) w2[t][k] = (a == k) ? (1.0f / (float)cn) : 0.f;
      }
    }
    __syncthreads();
  }

  // final weights -> global (k_cent consumes them)
  for (int e = t; e < NPTS * 8; e += 1024)
    wg[(size_t)b * (NPTS * 8) + e] = w2[e >> 3][e & 7];
}

// ---------------- k_cent: out[b][c][k] = sum_j w[k][j] * x[b][c][j] ----------------
__global__ __launch_bounds__(1024) void k_cent(const float* __restrict__ x,
                                               const float* __restrict__ wg,
                                               float* __restrict__ out, int nb) {
  const int b = blockIdx.x >> 3, s = blockIdx.x & 7;
  const int t = threadIdx.x, wv = t >> 6, lane = t & 63;
  const float* __restrict__ Mb = x + (size_t)b * (DIMS * NPTS);

  __shared__ float tile[64 * 145];       // 37.1 KB  [d][j] pad 145
  __shared__ float pool[KC][64][17];     // 26.1 KB
  __shared__ float w2[NPTS][8];          //  9.2 KB

  for (int e = t; e < NPTS * 8; e += 1024)
    w2[e >> 3][e & 7] = wg[(size_t)b * (NPTS * 8) + e];

  for (int dt = 0; dt < 4; ++dt) {
    float a0 = 0, a1 = 0, a2 = 0, a3 = 0, a4 = 0, a5 = 0;
#pragma unroll
    for (int h = 0; h < 2; ++h) {
      __syncthreads();                   // tile free (also covers w2 staging, dt=0)
#pragma unroll
      for (int i = 0; i < 9; ++i) {      // stage [64 d][144 j] coalesced
        const int e = t + 1024 * i;      // 0..9215
        const int d = e / 144, j = e - d * 144;
        tile[d * 145 + j] = Mb[(size_t)(s * 256 + dt * 64 + d) * NPTS + h * 144 + j];
      }
      __syncthreads();
      const int base = lane * 145 + wv * 9;   // lane <-> dim, wave <-> 9-pt group
#pragma unroll
      for (int r = 0; r < 9; ++r) {
        const float p = tile[base + r];
        const int j = h * 144 + wv * 9 + r;
        const float4 wA = *(const float4*)&w2[j][0];    // uniform broadcast
        const float2 wB = *(const float2*)&w2[j][4];
        a0 += wA.x * p; a1 += wA.y * p; a2 += wA.z * p;
        a3 += wA.w * p; a4 += wB.x * p; a5 += wB.y * p;
      }
    }
    pool[0][lane][wv] = a0; pool[1][lane][wv] = a1; pool[2][lane][wv] = a2;
    pool[3][lane][wv] = a3; pool[4][lane][wv] = a4; pool[5][lane][wv] = a5;
    __syncthreads();
    if (t < KC * 64) {                   // t = d*6 + k  -> coalesced 1536-B output run
      const int d = t / KC, k = t - d * KC;
      float sum = 0.f;
#pragma unroll
      for (int w = 0; w < 16; ++w) sum += pool[k][d][w];   // fixed order
      out[((size_t)b * DIMS + s * 256 + dt * 64 + d) * KC + k] = sum;
    }
    __syncthreads();                     // pool/out read done before next dt reuses
  }
}

extern "C" void kernel_launch(void* const* d_in, const int* in_sizes, int n_in,
                              void* d_out, int out_size, void* d_ws, size_t ws_size,
                              hipStream_t stream) {
  const float* x = (const float*)d_in[0];
  float* out     = (float*)d_out;
  const int nb   = in_sizes[0] / (DIMS * NPTS);   // 64
  const size_t N2 = (size_t)NPTS * NPTS;

  float* Gp = (float*)d_ws;                 // [KSPL][nb][288][288] = 42.5 MB
  float* G  = Gp + (size_t)KSPL * nb * N2;  // [nb][288][288]       = 21.2 MB
  float* wg = G + (size_t)nb * N2;          // [nb][288][8]

  hipLaunchKernelGGL(k_gram,  dim3(nb * NTP * KSPL), dim3(256),  0, stream, x, Gp, nb);
  hipLaunchKernelGGL(k_gsum,  dim3(nb * NTP),        dim3(256),  0, stream, Gp, G, nb);
  hipLaunchKernelGGL(k_lloyd, dim3(nb),              dim3(1024), 0, stream, G, wg, nb);
  hipLaunchKernelGGL(k_cent,  dim3(nb * 8),          dim3(1024), 0, stream, x, wg, out, nb);
}

// Round 15
// 468.287 us; speedup vs baseline: 1.7164x; 1.7164x over previous
//
#include <hip/hip_runtime.h>

#define NPTS 288
#define DIMS 2048
#define KC   6
#define N_IT 25

// ---------------- k_gram: partial G = A^T A, UPPER tile-pairs only ----------------
// (round-12 config, verbatim: proven 260 us at its LDS-feed ceiling, VGPR 92)
#define GT   96
#define KB   32
#define KSPL 2
#define KPS  (DIMS / KSPL)   // 1024
#define NCH  (KPS / KB)      // 32 chunks
#define NTP  6               // upper tile-pairs: (0,0)(0,1)(0,2)(1,1)(1,2)(2,2)

#define GLD16(gp, lp) __builtin_amdgcn_global_load_lds(                      \
    (const __attribute__((address_space(1))) void*)(gp),                     \
    (__attribute__((address_space(3))) void*)(lp), 16, 0, 0)

__global__ __launch_bounds__(256, 2) void k_gram(const float* __restrict__ x,
                                                 float* __restrict__ Gp, int nb) {
  const int bid = blockIdx.x;
  const int b  = bid / (NTP * KSPL);
  const int r0 = bid - b * (NTP * KSPL);
  const int ks = r0 / NTP, pr = r0 - ks * NTP;
  const int ti = (pr < 3) ? 0 : ((pr < 5) ? 1 : 2);
  const int tj = (pr < 3) ? pr : ((pr < 5) ? (pr - 2) : 2);
  const int t = threadIdx.x;
  const int tr = t >> 4, tc = t & 15;
  const int w = t >> 6, l = t & 63;
  const float* __restrict__ xb = x + (size_t)b * (DIMS * NPTS);
  float* __restrict__ Gb = Gp + ((size_t)ks * nb + b) * (NPTS * NPTS);

  __shared__ __attribute__((aligned(16))) float bufA[2][KB][GT];   // 24.6 KB
  __shared__ __attribute__((aligned(16))) float bufB[2][KB][GT];   // 24.6 KB

  int off[3];
#pragma unroll
  for (int iq = 0; iq < 3; ++iq) {
    const int e = (w * 3 + iq) * 256 + 4 * l;
    off[iq] = (e / GT) * NPTS + (e - (e / GT) * GT);
  }
  const float* __restrict__ baseA = xb + (size_t)(ks * KPS) * NPTS + ti * GT;
  const float* __restrict__ baseB = xb + (size_t)(ks * KPS) * NPTS + tj * GT;

  float acc[6][6];
#pragma unroll
  for (int ii = 0; ii < 6; ++ii)
#pragma unroll
    for (int jj = 0; jj < 6; ++jj) acc[ii][jj] = 0.f;

  auto stage = [&](int n, int c) {
#pragma unroll
    for (int iq = 0; iq < 3; ++iq) {
      const int o   = off[iq] + c * (KB * NPTS);
      const int lw  = (w * 3 + iq) * 256;
      GLD16(baseA + o, &bufA[n][0][0] + lw);
      GLD16(baseB + o, &bufB[n][0][0] + lw);
    }
  };

  stage(0, 0);
  __syncthreads();
  int n = 0;
  for (int c = 0; c < NCH; ++c) {
    if (c + 1 < NCH) stage(n ^ 1, c + 1);
#pragma unroll
    for (int kk = 0; kk < KB; ++kk) {
      float af[6], bf[6];
      const float2 a01 = *(const float2*)&bufA[n][kk][6 * tr];
      const float2 a23 = *(const float2*)&bufA[n][kk][6 * tr + 2];
      const float2 a45 = *(const float2*)&bufA[n][kk][6 * tr + 4];
      const float2 b01 = *(const float2*)&bufB[n][kk][6 * tc];
      const float2 b23 = *(const float2*)&bufB[n][kk][6 * tc + 2];
      const float2 b45 = *(const float2*)&bufB[n][kk][6 * tc + 4];
      af[0] = a01.x; af[1] = a01.y; af[2] = a23.x; af[3] = a23.y; af[4] = a45.x; af[5] = a45.y;
      bf[0] = b01.x; bf[1] = b01.y; bf[2] = b23.x; bf[3] = b23.y; bf[4] = b45.x; bf[5] = b45.y;
#pragma unroll
      for (int ii = 0; ii < 6; ++ii)
#pragma unroll
        for (int jj = 0; jj < 6; ++jj) acc[ii][jj] += af[ii] * bf[jj];
    }
    __syncthreads();
    n ^= 1;
  }

#pragma unroll
  for (int ii = 0; ii < 6; ++ii) {
    const int ri = ti * GT + 6 * tr + ii;
#pragma unroll
    for (int jj = 0; jj < 6; ++jj)
      Gb[(size_t)ri * NPTS + tj * GT + 6 * tc + jj] = acc[ii][jj];
  }
}

// ---------------- k_gsum: G = Gp0 + Gp1, all-coalesced mirror via LDS bounce ----------------
__global__ __launch_bounds__(256) void k_gsum(const float* __restrict__ Gp,
                                              float* __restrict__ G, int nb) {
  const int bid = blockIdx.x;
  const int b = bid / NTP, pr = bid - b * NTP;
  const int ti = (pr < 3) ? 0 : ((pr < 5) ? 1 : 2);
  const int tj = (pr < 3) ? pr : ((pr < 5) ? (pr - 2) : 2);
  const int t = threadIdx.x;
  const size_t N2 = (size_t)NPTS * NPTS;
  const size_t p1 = (size_t)nb * N2;
  const float* __restrict__ s0 = Gp + (size_t)b * N2;
  const float* __restrict__ s1 = Gp + p1 + (size_t)b * N2;
  float* __restrict__ Gb = G + (size_t)b * N2;

  __shared__ float tl[GT * 97];   // 37.2 KB

#pragma unroll
  for (int q = 0; q < 36; ++q) {
    const int e = q * 256 + t;           // 0..9215
    const int lr = e / GT, lc = e - lr * GT;
    const size_t idx = (size_t)(ti * GT + lr) * NPTS + tj * GT + lc;
    const float v = s0[idx] + s1[idx];   // fixed order: deterministic
    Gb[idx] = v;                         // coalesced
    tl[lr * 97 + lc] = v;                // stride-1 LDS write
  }
  if (ti == tj) return;                  // block-uniform: symmetric tile, no mirror
  __syncthreads();
#pragma unroll
  for (int q = 0; q < 36; ++q) {
    const int e = q * 256 + t;
    const int lr = e / GT, lc = e - lr * GT;     // output-local row/col at (tj,ti)
    Gb[(size_t)(tj * GT + lr) * NPTS + ti * GT + lc] = tl[lc * 97 + lr];  // coalesced out
  }
}

// ---------------- k_lloyd: all 25 Lloyd iterations on G (dense u, round-12) ----------------
// Round-14 lesson: the sparse gather put a data-dependent scalar branch between
// each global load and its use -> loads serialized at ~200cy each (544 us).
// Dense branch-free u-step lets the compiler pipeline all 96 loads. Reverted.
__global__ __launch_bounds__(1024) void k_lloyd(const float* __restrict__ G,
                                                float* __restrict__ wg, int nb) {
  const int b = blockIdx.x;
  const int t = threadIdx.x, wv = t >> 6, lane = t & 63;
  const float* __restrict__ Gb = G + (size_t)b * (NPTS * NPTS);

  __shared__ float w2[NPTS][8];          //  9.2 KB  weights [point][k], pad 8
  __shared__ float pool[KC][NPTS][5];    // 34.6 KB  u partials (3 used, pad 5)
  __shared__ float u[KC][NPTS];          //  6.9 KB  u[k][i] = p_i . c_k
  __shared__ int assign_s[NPTS];
  __shared__ float csq[KC];
  __shared__ int cnt_i[KC];

  // init: w_k = e_k  (centers0 = first KC points)
  for (int e = t; e < NPTS * 8; e += 1024) {
    const int i = e >> 3, k = e & 7;
    w2[i][k] = (k < KC && i == k) ? 1.f : 0.f;
  }
  __syncthreads();

  for (int it = 0; it < N_IT; ++it) {
    // ---- u = G * w : waves 0-14, jg = point-column third, lanes <-> rows ----
    {
      const int jg = t / 320;              // wave-uniform (320 = 5 waves)
      const int i  = t - jg * 320;
      if (t < 960 && i < NPTS) {
        float a0 = 0, a1 = 0, a2 = 0, a3 = 0, a4 = 0, a5 = 0;
        const float* __restrict__ gp = Gb + (size_t)(jg * 96) * NPTS + i;
        for (int jj = 0; jj < 96; ++jj) {
          const float g = gp[(size_t)jj * NPTS];            // coalesced (rows of G)
          const int j = jg * 96 + jj;
          const float4 wA = *(const float4*)&w2[j][0];      // uniform broadcast
          const float2 wB = *(const float2*)&w2[j][4];
          a0 += wA.x * g; a1 += wA.y * g; a2 += wA.z * g;
          a3 += wA.w * g; a4 += wB.x * g; a5 += wB.y * g;
        }
        pool[0][i][jg] = a0; pool[1][i][jg] = a1; pool[2][i][jg] = a2;
        pool[3][i][jg] = a3; pool[4][i][jg] = a4; pool[5][i][jg] = a5;
      }
    }
    __syncthreads();
    // ---- u reduce (fixed order) ----
    for (int e = t; e < KC * NPTS; e += 1024) {
      const int k = e / NPTS, i = e - k * NPTS;
      u[k][i] = pool[k][i][0] + pool[k][i][1] + pool[k][i][2];
    }
    if (t >= 960 && t < 960 + KC) cnt_i[t - 960] = 0;   // wave 15: reset counts
    __syncthreads();
    // ---- csq_k = w_k^T u_k : wave k, lane-strided + shuffle tree (fixed order) ----
    if (wv < KC) {
      float s = 0.f;
      for (int i = lane; i < NPTS; i += 64) s += w2[i][wv] * u[wv][i];
#pragma unroll
      for (int off = 32; off; off >>= 1) s += __shfl_xor(s, off, 64);
      if (lane == 0) csq[wv] = s;
    }
    __syncthreads();
    // ---- scores + argmin + counts ----
    int myA = -1;
    if (t < NPTS) {
      float best = 0.f;
      int bi = 0;
#pragma unroll
      for (int k = 0; k < KC; ++k) {
        const float sc = 0.5f * csq[k] - u[k][t];   // argmin_k(dist) equivalent
        if (k == 0 || sc < best) { best = sc; bi = k; }   // strict < : first-min
      }
      assign_s[t] = bi;
      myA = bi;
    }
    if (t < 320) {   // waves 0-4, uniform predicate; int atomics: deterministic
#pragma unroll
      for (int k = 0; k < KC; ++k) {
        unsigned long long m = __ballot(myA == k);
        if (lane == 0) atomicAdd(&cnt_i[k], (int)__popcll(m));
      }
    }
    __syncthreads();
    // ---- w update: live clusters get a_k/n_k, empty keep old weights ----
    if (t < NPTS) {
      const int a = assign_s[t];
#pragma unroll
      for (int k = 0; k < KC; ++k) {
        const int cn = cnt_i[k];
        if (cn > 0) w2[t][k] = (a == k) ? (1.0f / (float)cn) : 0.f;
      }
    }
    __syncthreads();
  }

  // final weights -> global (k_cent consumes them)
  for (int e = t; e < NPTS * 8; e += 1024)
    wg[(size_t)b * (NPTS * 8) + e] = w2[e >> 3][e & 7];
}

// ---------------- k_cent: out[b][c][k] = sum_j w[k][j] * x[b][c][j] ----------------
__global__ __launch_bounds__(1024) void k_cent(const float* __restrict__ x,
                                               const float* __restrict__ wg,
                                               float* __restrict__ out, int nb) {
  const int b = blockIdx.x >> 3, s = blockIdx.x & 7;
  const int t = threadIdx.x, wv = t >> 6, lane = t & 63;
  const float* __restrict__ Mb = x + (size_t)b * (DIMS * NPTS);

  __shared__ float tile[64 * 145];       // 37.1 KB  [d][j] pad 145
  __shared__ float pool[KC][64][17];     // 26.1 KB
  __shared__ float w2[NPTS][8];          //  9.2 KB

  for (int e = t; e < NPTS * 8; e += 1024)
    w2[e >> 3][e & 7] = wg[(size_t)b * (NPTS * 8) + e];

  for (int dt = 0; dt < 4; ++dt) {
    float a0 = 0, a1 = 0, a2 = 0, a3 = 0, a4 = 0, a5 = 0;
#pragma unroll
    for (int h = 0; h < 2; ++h) {
      __syncthreads();                   // tile free (also covers w2 staging, dt=0)
#pragma unroll
      for (int i = 0; i < 9; ++i) {      // stage [64 d][144 j] coalesced
        const int e = t + 1024 * i;      // 0..9215
        const int d = e / 144, j = e - d * 144;
        tile[d * 145 + j] = Mb[(size_t)(s * 256 + dt * 64 + d) * NPTS + h * 144 + j];
      }
      __syncthreads();
      const int base = lane * 145 + wv * 9;   // lane <-> dim, wave <-> 9-pt group
#pragma unroll
      for (int r = 0; r < 9; ++r) {
        const float p = tile[base + r];
        const int j = h * 144 + wv * 9 + r;
        const float4 wA = *(const float4*)&w2[j][0];    // uniform broadcast
        const float2 wB = *(const float2*)&w2[j][4];
        a0 += wA.x * p; a1 += wA.y * p; a2 += wA.z * p;
        a3 += wA.w * p; a4 += wB.x * p; a5 += wB.y * p;
      }
    }
    pool[0][lane][wv] = a0; pool[1][lane][wv] = a1; pool[2][lane][wv] = a2;
    pool[3][lane][wv] = a3; pool[4][lane][wv] = a4; pool[5][lane][wv] = a5;
    __syncthreads();
    if (t < KC * 64) {                   // t = d*6 + k  -> coalesced 1536-B output run
      const int d = t / KC, k = t - d * KC;
      float sum = 0.f;
#pragma unroll
      for (int w = 0; w < 16; ++w) sum += pool[k][d][w];   // fixed order
      out[((size_t)b * DIMS + s * 256 + dt * 64 + d) * KC + k] = sum;
    }
    __syncthreads();                     // pool/out read done before next dt reuses
  }
}

extern "C" void kernel_launch(void* const* d_in, const int* in_sizes, int n_in,
                              void* d_out, int out_size, void* d_ws, size_t ws_size,
                              hipStream_t stream) {
  const float* x = (const float*)d_in[0];
  float* out     = (float*)d_out;
  const int nb   = in_sizes[0] / (DIMS * NPTS);   // 64
  const size_t N2 = (size_t)NPTS * NPTS;

  float* Gp = (float*)d_ws;                 // [KSPL][nb][288][288] = 42.5 MB
  float* G  = Gp + (size_t)KSPL * nb * N2;  // [nb][288][288]       = 21.2 MB
  float* wg = G + (size_t)nb * N2;          // [nb][288][8]

  hipLaunchKernelGGL(k_gram,  dim3(nb * NTP * KSPL), dim3(256),  0, stream, x, Gp, nb);
  hipLaunchKernelGGL(k_gsum,  dim3(nb * NTP),        dim3(256),  0, stream, Gp, G, nb);
  hipLaunchKernelGGL(k_lloyd, dim3(nb),              dim3(1024), 0, stream, G, wg, nb);
  hipLaunchKernelGGL(k_cent,  dim3(nb * 8),          dim3(1024), 0, stream, x, wg, out, nb);
}